// Round 5
// baseline (534.834 us; speedup 1.0000x reference)
//
#include <hip/hip_runtime.h>
#include <hip/hip_bf16.h>
#include <hip/hip_cooperative_groups.h>

namespace cg = cooperative_groups;

typedef __bf16 bf16_t;
typedef __attribute__((ext_vector_type(8))) __bf16 bf16x8;
typedef __attribute__((ext_vector_type(4))) float f32x4;

#define EPSF 1e-5f

#define CVT8(dst, s0, s1)                                                      \
    dst[0]=(bf16_t)s0.x; dst[1]=(bf16_t)s0.y; dst[2]=(bf16_t)s0.z; dst[3]=(bf16_t)s0.w; \
    dst[4]=(bf16_t)s1.x; dst[5]=(bf16_t)s1.y; dst[6]=(bf16_t)s1.z; dst[7]=(bf16_t)s1.w;

// ===========================================================================
// Single cooperative mega-kernel. Grid 512 x 256 (2 blocks/CU co-resident).
// Stage A: blocks [0,128)   ai GEMM tile (both n-tiles, B-frag reused) + ej
//                           GEMV folded + attention-logit epilogue -> lp
//          blocks [128,256) fh GEMM tile (both n-tiles)             -> fh_out
//          blocks [256,512) fi GEMV, 8 rows each                    -> fi_out
// Stage B: blocks [0,32) frs ; [32,40) softmax+merged
// Stage C: blocks [0,256) W_merge GEMV 8 rows ; [256,264) fc
// Stage D: all 512 blocks: LN+tanh+concat xcat in LDS, W_iou GEMV 12 rows
// Stage E: block 0: fused tail -> out
// MFMA 16x16x32 bf16 (fp32 inputs converted on the fly, fp32 accumulate).
// A-frag: lane holds A[m=lane&15][k=quad*8+j]; B-frag: B[k][n=lane&15]
// D: lane L reg r -> row=(L>>4)*4+r, col=L&15
// ===========================================================================
__global__ __launch_bounds__(256, 2) void mega(
    const float* __restrict__ input, const float* __restrict__ hiddens,
    const float* __restrict__ cells, const float* __restrict__ external,
    const float* __restrict__ W_ai, const float* __restrict__ W_attn,
    const float* __restrict__ W_merge, const float* __restrict__ W_iou,
    const float* __restrict__ W_fi, const float* __restrict__ W_fh,
    const float* __restrict__ g_merge, const float* __restrict__ b_merge,
    const float* __restrict__ g_f, const float* __restrict__ b_f,
    const float* __restrict__ g_i, const float* __restrict__ b_i,
    const float* __restrict__ g_o, const float* __restrict__ b_o,
    const float* __restrict__ g_u, const float* __restrict__ b_u,
    const float* __restrict__ g_c, const float* __restrict__ b_c,
    float* __restrict__ lp, float* __restrict__ fh_out, float* __restrict__ fi_out,
    float* __restrict__ frs, float* __restrict__ merged, float* __restrict__ mm,
    float* __restrict__ fc, float* __restrict__ iou, float* __restrict__ out)
{
    cg::grid_group grid = cg::this_grid();
    __shared__ __align__(16) float sm[4608];   // 18 KB, reused per stage

    const int b    = blockIdx.x;
    const int tid  = threadIdx.x;
    const int wave = tid >> 6;
    const int lane = tid & 63;

    // ================= Stage A =================
    if (b < 256) {
        const bool is_ai = (b < 128);
        const int  jt    = is_ai ? b : b - 128;
        const int  l15   = lane & 15;
        const int  quad  = lane >> 4;
        const int  k0    = wave * 512;                 // K=2048, 4-way wave split
        const int  wstride = is_ai ? 4096 : 2048;
        const float* W  = is_ai ? W_ai : W_fh;

        const float* ap0 = hiddens + (size_t)l15 * 2048 + quad * 8 + k0;
        const float* ap1 = ap0 + 16 * 2048;
        const float* bp  = W + (size_t)(jt * 16 + l15) * wstride + quad * 8 + k0;

        f32x4 acc0 = {0.f,0.f,0.f,0.f}, acc1 = {0.f,0.f,0.f,0.f};

        if (is_ai) {
            const float* ep = bp + 2048;               // W_ai[row][2048+..]
            const float* xp = external + quad * 8 + k0;
            float ejacc = 0.f;
            for (int k = 0; k < 512; k += 32) {
                float4 b0 = *(const float4*)(bp + k);
                float4 b1 = *(const float4*)(bp + k + 4);
                float4 a0 = *(const float4*)(ap0 + k);
                float4 a1 = *(const float4*)(ap0 + k + 4);
                float4 c0 = *(const float4*)(ap1 + k);
                float4 c1 = *(const float4*)(ap1 + k + 4);
                bf16x8 bv, av0, av1;
                CVT8(bv, b0, b1); CVT8(av0, a0, a1); CVT8(av1, c0, c1);
                acc0 = __builtin_amdgcn_mfma_f32_16x16x32_bf16(av0, bv, acc0, 0, 0, 0);
                acc1 = __builtin_amdgcn_mfma_f32_16x16x32_bf16(av1, bv, acc1, 0, 0, 0);
                float4 e0 = *(const float4*)(ep + k);
                float4 e1 = *(const float4*)(ep + k + 4);
                float4 x0 = *(const float4*)(xp + k);
                float4 x1 = *(const float4*)(xp + k + 4);
                ejacc += e0.x*x0.x + e0.y*x0.y + e0.z*x0.z + e0.w*x0.w
                       + e1.x*x1.x + e1.y*x1.y + e1.z*x1.z + e1.w*x1.w;
            }
            ejacc += __shfl_xor(ejacc, 16, 64);
            ejacc += __shfl_xor(ejacc, 32, 64);
            if (quad == 0) sm[2048 + wave * 16 + l15] = ejacc;
        } else {
            for (int k = 0; k < 512; k += 32) {
                float4 b0 = *(const float4*)(bp + k);
                float4 b1 = *(const float4*)(bp + k + 4);
                float4 a0 = *(const float4*)(ap0 + k);
                float4 a1 = *(const float4*)(ap0 + k + 4);
                float4 c0 = *(const float4*)(ap1 + k);
                float4 c1 = *(const float4*)(ap1 + k + 4);
                bf16x8 bv, av0, av1;
                CVT8(bv, b0, b1); CVT8(av0, a0, a1); CVT8(av1, c0, c1);
                acc0 = __builtin_amdgcn_mfma_f32_16x16x32_bf16(av0, bv, acc0, 0, 0, 0);
                acc1 = __builtin_amdgcn_mfma_f32_16x16x32_bf16(av1, bv, acc1, 0, 0, 0);
            }
        }

        #pragma unroll
        for (int r = 0; r < 4; ++r) {
            sm[wave * 512 +       (quad * 4 + r) * 16 + l15] = acc0[r];
            sm[wave * 512 + 256 + (quad * 4 + r) * 16 + l15] = acc1[r];
        }
        __syncthreads();

        int row = tid >> 4, col = tid & 15;
        float s0  = sm[row*16+col]     + sm[512+row*16+col]
                  + sm[1024+row*16+col] + sm[1536+row*16+col];
        float s1v = sm[256+row*16+col] + sm[768+row*16+col]
                  + sm[1280+row*16+col] + sm[1792+row*16+col];

        if (is_ai) {
            float ej = sm[2048+col] + sm[2064+col] + sm[2080+col] + sm[2096+col];
            float wat = W_attn[jt * 16 + col];
            float lg0 = tanhf(s0  + ej) * wat;
            float lg1 = tanhf(s1v + ej) * wat;
            #pragma unroll
            for (int m = 1; m < 16; m <<= 1) {
                lg0 += __shfl_xor(lg0, m, 64);
                lg1 += __shfl_xor(lg1, m, 64);
            }
            if (col == 0) {
                lp[jt * 32 + row]      = lg0;
                lp[jt * 32 + 16 + row] = lg1;
            }
        } else {
            fh_out[(size_t)row * 2048 + jt * 16 + col]        = s0;
            fh_out[(size_t)(16 + row) * 2048 + jt * 16 + col] = s1v;
        }
    } else {
        // fi GEMV: 256 blocks, 8 rows each (2 per wave)
        int bb = b - 256;
        #pragma unroll
        for (int r = 0; r < 2; ++r) {
            int row = bb * 8 + wave * 2 + r;
            const float4* wp = (const float4*)(W_fi + (size_t)row * 2048) + lane;
            const float4* xp = (const float4*)input + lane;
            float a = 0.f;
            #pragma unroll
            for (int k = 0; k < 512; k += 64) {
                float4 w = wp[k], v = xp[k];
                a += w.x*v.x + w.y*v.y + w.z*v.z + w.w*v.w;
            }
            #pragma unroll
            for (int off = 32; off; off >>= 1) a += __shfl_down(a, off, 64);
            if (lane == 0) fi_out[row] = a;
        }
    }
    grid.sync();

    // ================= Stage B =================
    if (b < 32) {
        float* s1 = sm; float* s2 = sm + 256;
        int n = b;
        float sum = 0.f, sq = 0.f;
        #pragma unroll
        for (int i = 0; i < 8; ++i) {
            int h = tid * 8 + i;
            float v = fi_out[h] + fh_out[n * 2048 + h];
            sum += v; sq += v * v;
        }
        s1[tid] = sum; s2[tid] = sq;
        __syncthreads();
        for (int off = 128; off; off >>= 1) {
            if (tid < off) { s1[tid] += s1[tid + off]; s2[tid] += s2[tid + off]; }
            __syncthreads();
        }
        if (tid == 0) {
            const float inv = 1.f / 2048.f;
            float mean = s1[0] * inv;
            frs[n * 2]     = mean;
            frs[n * 2 + 1] = rsqrtf(s2[0] * inv - mean * mean + EPSF);
        }
    } else if (b < 40) {
        float* lred  = sm;        // [32][8]
        float* attnw = sm + 256;  // [32]
        int n = tid >> 3, sl = tid & 7;
        float p = 0.f;
        #pragma unroll
        for (int m = 0; m < 16; ++m) p += lp[(sl * 16 + m) * 32 + n];
        lred[n * 8 + sl] = p;
        __syncthreads();
        if (sl == 0) {
            float lg = 0.f;
            #pragma unroll
            for (int m = 0; m < 8; ++m) lg += lred[n * 8 + m];
            lred[n * 8] = lg;
        }
        __syncthreads();
        if (tid < 32) {
            float mx = -1e30f;
            for (int m = 0; m < 32; ++m) mx = fmaxf(mx, lred[m * 8]);
            float ssum = 0.f;
            for (int m = 0; m < 32; ++m) ssum += expf(lred[m * 8] - mx);
            attnw[tid] = expf(lred[tid * 8] - mx) / ssum;
        }
        __syncthreads();
        int h = (b - 32) * 256 + tid;
        float acc = 0.f;
        #pragma unroll 8
        for (int n2 = 0; n2 < 32; ++n2) acc += attnw[n2] * hiddens[n2 * 2048 + h];
        merged[h] = acc;
    }
    grid.sync();

    // ================= Stage C =================
    if (b < 256) {
        #pragma unroll
        for (int r = 0; r < 2; ++r) {
            int row = b * 8 + wave * 2 + r;
            const float4* wp = (const float4*)(W_merge + (size_t)row * 2048) + lane;
            const float4* xp = (const float4*)merged + lane;
            float a = 0.f;
            #pragma unroll
            for (int k = 0; k < 512; k += 64) {
                float4 w = wp[k], v = xp[k];
                a += w.x*v.x + w.y*v.y + w.z*v.z + w.w*v.w;
            }
            #pragma unroll
            for (int off = 32; off; off >>= 1) a += __shfl_down(a, off, 64);
            if (lane == 0) mm[row] = a;
        }
    } else if (b < 264) {
        int h = (b - 256) * 256 + tid;
        float g = g_f[h], bb2 = b_f[h], f_i = fi_out[h];
        float acc = 0.f;
        for (int n = 0; n < 32; ++n) {
            float v = (f_i + fh_out[n * 2048 + h] - frs[n * 2]) * frs[n * 2 + 1] * g + bb2;
            acc += (1.f / (1.f + expf(-v))) * cells[n * 2048 + h];
        }
        fc[h] = acc;
    }
    grid.sync();

    // ================= Stage D =================
    {
        float* xcat = sm;            // [4096]
        float* s1 = sm + 4096; float* s2 = sm + 4352;
        float v[8]; float sum = 0.f, sq = 0.f;
        #pragma unroll
        for (int i = 0; i < 8; ++i) {
            v[i] = mm[tid * 8 + i]; sum += v[i]; sq += v[i] * v[i];
        }
        s1[tid] = sum; s2[tid] = sq;
        __syncthreads();
        for (int off = 128; off; off >>= 1) {
            if (tid < off) { s1[tid] += s1[tid + off]; s2[tid] += s2[tid + off]; }
            __syncthreads();
        }
        const float inv = 1.f / 2048.f;
        float mean = s1[0] * inv;
        float r = rsqrtf(s2[0] * inv - mean * mean + EPSF);
        #pragma unroll
        for (int i = 0; i < 8; ++i) {
            int h = tid * 8 + i;
            xcat[h]        = input[h];
            xcat[2048 + h] = tanhf((v[i] - mean) * r * g_merge[h] + b_merge[h]);
        }
        __syncthreads();

        #pragma unroll
        for (int rr = 0; rr < 3; ++rr) {
            int row = b * 12 + wave * 3 + rr;
            const float4* wp = (const float4*)(W_iou + (size_t)row * 4096) + lane;
            const float4* xp = (const float4*)xcat + lane;
            float a = 0.f;
            #pragma unroll
            for (int k = 0; k < 1024; k += 64) {
                float4 w = wp[k], x = xp[k];
                a += w.x*x.x + w.y*x.y + w.z*x.z + w.w*x.w;
            }
            #pragma unroll
            for (int off = 32; off; off >>= 1) a += __shfl_down(a, off, 64);
            if (lane == 0) iou[row] = a;
        }
    }
    grid.sync();

    // ================= Stage E =================
    if (b == 0) {
        int t = tid;
        float vi[8], vo[8], vu[8];
        float si = 0, qi = 0, so = 0, qo = 0, su = 0, qu = 0;
        #pragma unroll
        for (int i = 0; i < 8; ++i) {
            int h = t * 8 + i;
            vi[i] = iou[h]; vo[i] = iou[2048 + h]; vu[i] = iou[4096 + h];
            si += vi[i]; qi += vi[i] * vi[i];
            so += vo[i]; qo += vo[i] * vo[i];
            su += vu[i]; qu += vu[i] * vu[i];
        }
        sm[t] = si; sm[256 + t] = qi; sm[512 + t] = so;
        sm[768 + t] = qo; sm[1024 + t] = su; sm[1280 + t] = qu;
        __syncthreads();
        for (int off = 128; off; off >>= 1) {
            if (t < off) {
                #pragma unroll
                for (int c = 0; c < 6; ++c) sm[c * 256 + t] += sm[c * 256 + t + off];
            }
            __syncthreads();
        }
        const float inv = 1.f / 2048.f;
        float mi = sm[0] * inv,    ri = rsqrtf(sm[256] * inv - mi * mi + EPSF);
        float mo = sm[512] * inv,  ro = rsqrtf(sm[768] * inv - mo * mo + EPSF);
        float mu = sm[1024] * inv, ru = rsqrtf(sm[1280] * inv - mu * mu + EPSF);
        __syncthreads();

        float o_[8], v_[8];
        float sv = 0, qv = 0;
        #pragma unroll
        for (int i = 0; i < 8; ++i) {
            int h = t * 8 + i;
            float ivl = 1.f / (1.f + expf(-((vi[i] - mi) * ri * g_i[h] + b_i[h])));
            o_[i]     = 1.f / (1.f + expf(-((vo[i] - mo) * ro * g_o[h] + b_o[h])));
            float uvl = tanhf((vu[i] - mu) * ru * g_u[h] + b_u[h]);
            v_[i] = ivl * uvl + fc[h];
            sv += v_[i]; qv += v_[i] * v_[i];
        }
        sm[t] = sv; sm[256 + t] = qv;
        __syncthreads();
        for (int off = 128; off; off >>= 1) {
            if (t < off) { sm[t] += sm[t + off]; sm[256 + t] += sm[256 + t + off]; }
            __syncthreads();
        }
        float mc = sm[0] * inv, rc = rsqrtf(sm[256] * inv - mc * mc + EPSF);
        #pragma unroll
        for (int i = 0; i < 8; ++i) {
            int h = t * 8 + i;
            float nc = (v_[i] - mc) * rc * g_c[h] + b_c[h];
            out[h]        = o_[i] * tanhf(nc);   // new_h
            out[2048 + h] = nc;                  // new_cell
        }
    }
}

// ---------------------------------------------------------------------------
extern "C" void kernel_launch(void* const* d_in, const int* in_sizes, int n_in,
                              void* d_out, int out_size, void* d_ws, size_t ws_size,
                              hipStream_t stream)
{
    const float* input    = (const float*)d_in[0];
    const float* hiddens  = (const float*)d_in[1];
    const float* cells    = (const float*)d_in[2];
    const float* external = (const float*)d_in[3];
    const float* W_ai     = (const float*)d_in[4];
    const float* W_attn   = (const float*)d_in[5];
    const float* W_merge  = (const float*)d_in[6];
    const float* W_iou    = (const float*)d_in[7];
    const float* W_fi     = (const float*)d_in[8];
    const float* W_fh     = (const float*)d_in[9];
    const float* g_merge  = (const float*)d_in[10];
    const float* b_merge  = (const float*)d_in[11];
    const float* g_f      = (const float*)d_in[12];
    const float* b_f      = (const float*)d_in[13];
    const float* g_i      = (const float*)d_in[14];
    const float* b_i      = (const float*)d_in[15];
    const float* g_o      = (const float*)d_in[16];
    const float* b_o      = (const float*)d_in[17];
    const float* g_u      = (const float*)d_in[18];
    const float* b_u      = (const float*)d_in[19];
    const float* g_c      = (const float*)d_in[20];
    const float* b_c      = (const float*)d_in[21];

    float* ws = (float*)d_ws;
    float* ws_lp     = ws;              // 4096
    float* ws_fh     = ws + 4096;       // 65536
    float* ws_fi     = ws + 69632;      // 2048
    float* ws_frs    = ws + 71680;      // 64
    float* ws_merged = ws + 71744;      // 2048
    float* ws_mm     = ws + 73792;      // 2048
    float* ws_fc     = ws + 75840;      // 2048
    float* ws_iou    = ws + 77888;      // 6144
    float* out = (float*)d_out;

    void* args[] = {
        (void*)&input, (void*)&hiddens, (void*)&cells, (void*)&external,
        (void*)&W_ai, (void*)&W_attn, (void*)&W_merge, (void*)&W_iou,
        (void*)&W_fi, (void*)&W_fh,
        (void*)&g_merge, (void*)&b_merge, (void*)&g_f, (void*)&b_f,
        (void*)&g_i, (void*)&b_i, (void*)&g_o, (void*)&b_o,
        (void*)&g_u, (void*)&b_u, (void*)&g_c, (void*)&b_c,
        (void*)&ws_lp, (void*)&ws_fh, (void*)&ws_fi, (void*)&ws_frs,
        (void*)&ws_merged, (void*)&ws_mm, (void*)&ws_fc, (void*)&ws_iou,
        (void*)&out
    };
    hipLaunchCooperativeKernel((void*)mega, dim3(512), dim3(256), args, 0, stream);
}

// Round 6
// 286.947 us; speedup vs baseline: 1.8639x; 1.8639x over previous
//
#include <hip/hip_runtime.h>
#include <hip/hip_bf16.h>

typedef __bf16 bf16_t;
typedef __attribute__((ext_vector_type(8))) __bf16 bf16x8;
typedef __attribute__((ext_vector_type(4))) float f32x4;

#define EPSF 1e-5f

#define CVT8(dst, s0, s1)                                                      \
    dst[0]=(bf16_t)s0.x; dst[1]=(bf16_t)s0.y; dst[2]=(bf16_t)s0.z; dst[3]=(bf16_t)s0.w; \
    dst[4]=(bf16_t)s1.x; dst[5]=(bf16_t)s1.y; dst[6]=(bf16_t)s1.z; dst[7]=(bf16_t)s1.w;

// ===========================================================================
// K1. Grid 512 x 256:
//   blocks [0,128):   ai GEMM tile jt (BOTH n-tiles, B-frag loaded once) +
//                     ej GEMV folded (once) + attention-logit epilogue -> lp
//   blocks [128,256)  fh GEMM tile jt (both n-tiles)                   -> fh_out
//   blocks [256,512)  fi GEMV, 8 rows each                             -> fi_out
// MFMA 16x16x32 bf16 (fp32 in, converted on the fly, fp32 accumulate).
// A-frag: lane holds A[m=lane&15][k=quad*8+j]; B-frag: B[k][n=lane&15]
// D: lane L reg r -> row=(L>>4)*4+r, col=L&15
// ===========================================================================
__global__ __launch_bounds__(256) void s1(
    const float* __restrict__ hiddens, const float* __restrict__ external,
    const float* __restrict__ input,
    const float* __restrict__ W_ai, const float* __restrict__ W_fh,
    const float* __restrict__ W_fi, const float* __restrict__ W_attn,
    float* __restrict__ lp, float* __restrict__ fh_out, float* __restrict__ fi_out)
{
    __shared__ __align__(16) float sm[2176];
    const int b    = blockIdx.x;
    const int tid  = threadIdx.x;
    const int wave = tid >> 6;
    const int lane = tid & 63;

    if (b < 256) {
        const bool is_ai = (b < 128);
        const int  jt    = is_ai ? b : b - 128;
        const int  l15   = lane & 15;
        const int  quad  = lane >> 4;
        const int  k0    = wave * 512;                 // K=2048, 4-way wave split
        const int  wstride = is_ai ? 4096 : 2048;
        const float* W  = is_ai ? W_ai : W_fh;

        const float* ap0 = hiddens + (size_t)l15 * 2048 + quad * 8 + k0;
        const float* ap1 = ap0 + 16 * 2048;
        const float* bp  = W + (size_t)(jt * 16 + l15) * wstride + quad * 8 + k0;

        f32x4 acc0 = {0.f,0.f,0.f,0.f}, acc1 = {0.f,0.f,0.f,0.f};

        if (is_ai) {
            const float* ep = bp + 2048;               // W_ai[row][2048+..]
            const float* xp = external + quad * 8 + k0;
            float ejacc = 0.f;
            for (int k = 0; k < 512; k += 32) {
                float4 b0 = *(const float4*)(bp + k);
                float4 b1 = *(const float4*)(bp + k + 4);
                float4 a0 = *(const float4*)(ap0 + k);
                float4 a1 = *(const float4*)(ap0 + k + 4);
                float4 c0 = *(const float4*)(ap1 + k);
                float4 c1 = *(const float4*)(ap1 + k + 4);
                bf16x8 bv, av0, av1;
                CVT8(bv, b0, b1); CVT8(av0, a0, a1); CVT8(av1, c0, c1);
                acc0 = __builtin_amdgcn_mfma_f32_16x16x32_bf16(av0, bv, acc0, 0, 0, 0);
                acc1 = __builtin_amdgcn_mfma_f32_16x16x32_bf16(av1, bv, acc1, 0, 0, 0);
                float4 e0 = *(const float4*)(ep + k);
                float4 e1 = *(const float4*)(ep + k + 4);
                float4 x0 = *(const float4*)(xp + k);
                float4 x1 = *(const float4*)(xp + k + 4);
                ejacc += e0.x*x0.x + e0.y*x0.y + e0.z*x0.z + e0.w*x0.w
                       + e1.x*x1.x + e1.y*x1.y + e1.z*x1.z + e1.w*x1.w;
            }
            ejacc += __shfl_xor(ejacc, 16, 64);
            ejacc += __shfl_xor(ejacc, 32, 64);
            if (quad == 0) sm[2048 + wave * 16 + l15] = ejacc;
        } else {
            for (int k = 0; k < 512; k += 32) {
                float4 b0 = *(const float4*)(bp + k);
                float4 b1 = *(const float4*)(bp + k + 4);
                float4 a0 = *(const float4*)(ap0 + k);
                float4 a1 = *(const float4*)(ap0 + k + 4);
                float4 c0 = *(const float4*)(ap1 + k);
                float4 c1 = *(const float4*)(ap1 + k + 4);
                bf16x8 bv, av0, av1;
                CVT8(bv, b0, b1); CVT8(av0, a0, a1); CVT8(av1, c0, c1);
                acc0 = __builtin_amdgcn_mfma_f32_16x16x32_bf16(av0, bv, acc0, 0, 0, 0);
                acc1 = __builtin_amdgcn_mfma_f32_16x16x32_bf16(av1, bv, acc1, 0, 0, 0);
            }
        }

        #pragma unroll
        for (int r = 0; r < 4; ++r) {
            sm[wave * 512 +       (quad * 4 + r) * 16 + l15] = acc0[r];
            sm[wave * 512 + 256 + (quad * 4 + r) * 16 + l15] = acc1[r];
        }
        __syncthreads();

        int row = tid >> 4, col = tid & 15;
        float s0  = sm[row*16+col]      + sm[512+row*16+col]
                  + sm[1024+row*16+col] + sm[1536+row*16+col];
        float s1v = sm[256+row*16+col]  + sm[768+row*16+col]
                  + sm[1280+row*16+col] + sm[1792+row*16+col];

        if (is_ai) {
            float ej = sm[2048+col] + sm[2064+col] + sm[2080+col] + sm[2096+col];
            float wat = W_attn[jt * 16 + col];
            float lg0 = tanhf(s0  + ej) * wat;
            float lg1 = tanhf(s1v + ej) * wat;
            #pragma unroll
            for (int m = 1; m < 16; m <<= 1) {
                lg0 += __shfl_xor(lg0, m, 64);
                lg1 += __shfl_xor(lg1, m, 64);
            }
            if (col == 0) {
                lp[jt * 32 + row]      = lg0;
                lp[jt * 32 + 16 + row] = lg1;
            }
        } else {
            fh_out[(size_t)row * 2048 + jt * 16 + col]        = s0;
            fh_out[(size_t)(16 + row) * 2048 + jt * 16 + col] = s1v;
        }
    } else {
        // fi GEMV: 256 blocks, 8 rows each (2 per wave)
        int bb = b - 256;
        #pragma unroll
        for (int r = 0; r < 2; ++r) {
            int row = bb * 8 + wave * 2 + r;
            const float4* wp = (const float4*)(W_fi + (size_t)row * 2048) + lane;
            const float4* xp = (const float4*)input + lane;
            float a = 0.f;
            #pragma unroll
            for (int k = 0; k < 512; k += 64) {
                float4 w = wp[k], v = xp[k];
                a += w.x*v.x + w.y*v.y + w.z*v.z + w.w*v.w;
            }
            #pragma unroll
            for (int off = 32; off; off >>= 1) a += __shfl_down(a, off, 64);
            if (lane == 0) fi_out[row] = a;
        }
    }
}

// ===========================================================================
// K2. Grid 288 x 256:
//   blocks [0,256):   rebuild attn+merged redundantly in LDS (lp reduce ->
//                     softmax -> merged[2048]), then W_merge GEMV 8 rows -> mm
//   blocks [256,288): per-child LN stats of fi+fh[n] -> frs
// ===========================================================================
__global__ __launch_bounds__(256) void s2(
    const float* __restrict__ lp, const float* __restrict__ hiddens,
    const float* __restrict__ W_merge,
    const float* __restrict__ fi, const float* __restrict__ fh,
    float* __restrict__ mm, float* __restrict__ frs)
{
    int b = blockIdx.x, t = threadIdx.x;
    if (b < 256) {
        __shared__ float lred[32][9];
        __shared__ float attnw[32];
        __shared__ __align__(16) float merged_s[2048];
        int n = t >> 3, sl = t & 7;
        float p = 0.f;
        #pragma unroll
        for (int m = 0; m < 16; ++m) p += lp[(sl * 16 + m) * 32 + n];
        lred[n][sl] = p;
        __syncthreads();
        if (t < 32) {
            float lg = 0.f;
            #pragma unroll
            for (int m = 0; m < 8; ++m) lg += lred[t][m];
            lred[t][8] = lg;
        }
        __syncthreads();
        if (t < 32) {
            float mx = -1e30f;
            for (int m = 0; m < 32; ++m) mx = fmaxf(mx, lred[m][8]);
            float ss = 0.f;
            for (int m = 0; m < 32; ++m) ss += expf(lred[m][8] - mx);
            attnw[t] = expf(lred[t][8] - mx) / ss;
        }
        __syncthreads();
        #pragma unroll
        for (int i = 0; i < 8; ++i) {
            int h = i * 256 + t;                       // coalesced
            float acc = 0.f;
            #pragma unroll 8
            for (int n2 = 0; n2 < 32; ++n2) acc += attnw[n2] * hiddens[n2 * 2048 + h];
            merged_s[h] = acc;
        }
        __syncthreads();

        int wave = t >> 6, lane = t & 63;
        #pragma unroll
        for (int r = 0; r < 2; ++r) {
            int row = b * 8 + wave * 2 + r;
            const float4* wp = (const float4*)(W_merge + (size_t)row * 2048) + lane;
            const float4* xp = (const float4*)merged_s + lane;
            float a = 0.f;
            #pragma unroll
            for (int k = 0; k < 512; k += 64) {
                float4 w = wp[k], v = xp[k];
                a += w.x*v.x + w.y*v.y + w.z*v.z + w.w*v.w;
            }
            #pragma unroll
            for (int off = 32; off; off >>= 1) a += __shfl_down(a, off, 64);
            if (lane == 0) mm[row] = a;
        }
    } else {
        __shared__ float s1a[256], s2a[256];
        int n = b - 256;
        float sum = 0.f, sq = 0.f;
        #pragma unroll
        for (int i = 0; i < 8; ++i) {
            int h = t * 8 + i;
            float v = fi[h] + fh[n * 2048 + h];
            sum += v; sq += v * v;
        }
        s1a[t] = sum; s2a[t] = sq;
        __syncthreads();
        for (int off = 128; off; off >>= 1) {
            if (t < off) { s1a[t] += s1a[t + off]; s2a[t] += s2a[t + off]; }
            __syncthreads();
        }
        if (t == 0) {
            const float inv = 1.f / 2048.f;
            float mean = s1a[0] * inv;
            frs[n * 2]     = mean;
            frs[n * 2 + 1] = rsqrtf(s2a[0] * inv - mean * mean + EPSF);
        }
    }
}

// ===========================================================================
// K3. Grid 520 x 256:
//   blocks [0,512):   xcat = [input ; tanh(LN(mm)*g+b)] in LDS (redundant),
//                     then W_iou GEMV 12 rows -> iou
//   blocks [512,520): fc[h] = sum_n sigmoid(LN_n(fi+fh)[h]*g+b)*cells[n][h]
// ===========================================================================
__global__ __launch_bounds__(256) void s3(
    const float* __restrict__ W_iou, const float* __restrict__ mm,
    const float* __restrict__ input, const float* __restrict__ g_merge,
    const float* __restrict__ b_merge,
    const float* __restrict__ fi, const float* __restrict__ fh,
    const float* __restrict__ frs, const float* __restrict__ g_f,
    const float* __restrict__ b_f, const float* __restrict__ cells,
    float* __restrict__ iou, float* __restrict__ fc)
{
    int b = blockIdx.x, t = threadIdx.x;
    if (b < 512) {
        __shared__ __align__(16) float xcat[4096];
        __shared__ float s1a[256], s2a[256];
        float v[8]; float sum = 0.f, sq = 0.f;
        #pragma unroll
        for (int i = 0; i < 8; ++i) {
            v[i] = mm[t * 8 + i]; sum += v[i]; sq += v[i] * v[i];
        }
        s1a[t] = sum; s2a[t] = sq;
        __syncthreads();
        for (int off = 128; off; off >>= 1) {
            if (t < off) { s1a[t] += s1a[t + off]; s2a[t] += s2a[t + off]; }
            __syncthreads();
        }
        const float inv = 1.f / 2048.f;
        float mean = s1a[0] * inv;
        float r = rsqrtf(s2a[0] * inv - mean * mean + EPSF);
        #pragma unroll
        for (int i = 0; i < 8; ++i) {
            int h = t * 8 + i;
            xcat[h]        = input[h];
            xcat[2048 + h] = tanhf((v[i] - mean) * r * g_merge[h] + b_merge[h]);
        }
        __syncthreads();

        int wave = t >> 6, lane = t & 63;
        #pragma unroll
        for (int rr = 0; rr < 3; ++rr) {
            int row = b * 12 + wave * 3 + rr;
            const float4* wp = (const float4*)(W_iou + (size_t)row * 4096) + lane;
            const float4* xp = (const float4*)xcat + lane;
            float a = 0.f;
            #pragma unroll
            for (int k = 0; k < 1024; k += 64) {
                float4 w = wp[k], x = xp[k];
                a += w.x*x.x + w.y*x.y + w.z*x.z + w.w*x.w;
            }
            #pragma unroll
            for (int off = 32; off; off >>= 1) a += __shfl_down(a, off, 64);
            if (lane == 0) iou[row] = a;
        }
    } else {
        int h = (b - 512) * 256 + t;
        float g = g_f[h], bb = b_f[h], f_i = fi[h];
        float acc = 0.f;
        for (int n = 0; n < 32; ++n) {
            float v = (f_i + fh[n * 2048 + h] - frs[n * 2]) * frs[n * 2 + 1] * g + bb;
            acc += (1.f / (1.f + expf(-v))) * cells[n * 2048 + h];
        }
        fc[h] = acc;
    }
}

// ===========================================================================
// K4: fused tail — i/o/u LN stats + gates, v = i*u + fc, LN(v). One block.
// ===========================================================================
__global__ __launch_bounds__(256) void s4_tail(
    const float* __restrict__ iou, const float* __restrict__ fc,
    const float* __restrict__ gi, const float* __restrict__ bi,
    const float* __restrict__ go, const float* __restrict__ bo,
    const float* __restrict__ gu, const float* __restrict__ bu,
    const float* __restrict__ gc, const float* __restrict__ bc,
    float* __restrict__ out)
{
    __shared__ float sA[6][256];
    int t = threadIdx.x;
    float vi[8], vo[8], vu[8];
    float si = 0, qi = 0, so = 0, qo = 0, su = 0, qu = 0;
    #pragma unroll
    for (int i = 0; i < 8; ++i) {
        int h = t * 8 + i;
        vi[i] = iou[h]; vo[i] = iou[2048 + h]; vu[i] = iou[4096 + h];
        si += vi[i]; qi += vi[i] * vi[i];
        so += vo[i]; qo += vo[i] * vo[i];
        su += vu[i]; qu += vu[i] * vu[i];
    }
    sA[0][t] = si; sA[1][t] = qi; sA[2][t] = so;
    sA[3][t] = qo; sA[4][t] = su; sA[5][t] = qu;
    __syncthreads();
    for (int off = 128; off; off >>= 1) {
        if (t < off) {
            #pragma unroll
            for (int c = 0; c < 6; ++c) sA[c][t] += sA[c][t + off];
        }
        __syncthreads();
    }
    const float inv = 1.f / 2048.f;
    float mi = sA[0][0] * inv, ri = rsqrtf(sA[1][0] * inv - mi * mi + EPSF);
    float mo = sA[2][0] * inv, ro = rsqrtf(sA[3][0] * inv - mo * mo + EPSF);
    float mu = sA[4][0] * inv, ru = rsqrtf(sA[5][0] * inv - mu * mu + EPSF);
    __syncthreads();

    float o_[8], v_[8];
    float sv = 0, qv = 0;
    #pragma unroll
    for (int i = 0; i < 8; ++i) {
        int h = t * 8 + i;
        float ivl = 1.f / (1.f + expf(-((vi[i] - mi) * ri * gi[h] + bi[h])));
        o_[i]     = 1.f / (1.f + expf(-((vo[i] - mo) * ro * go[h] + bo[h])));
        float uvl = tanhf((vu[i] - mu) * ru * gu[h] + bu[h]);
        v_[i] = ivl * uvl + fc[h];
        sv += v_[i]; qv += v_[i] * v_[i];
    }
    sA[0][t] = sv; sA[1][t] = qv;
    __syncthreads();
    for (int off = 128; off; off >>= 1) {
        if (t < off) { sA[0][t] += sA[0][t + off]; sA[1][t] += sA[1][t + off]; }
        __syncthreads();
    }
    float mc = sA[0][0] * inv, rc = rsqrtf(sA[1][0] * inv - mc * mc + EPSF);
    #pragma unroll
    for (int i = 0; i < 8; ++i) {
        int h = t * 8 + i;
        float nc = (v_[i] - mc) * rc * gc[h] + bc[h];
        out[h]        = o_[i] * tanhf(nc);   // new_h
        out[2048 + h] = nc;                  // new_cell
    }
}

// ---------------------------------------------------------------------------
extern "C" void kernel_launch(void* const* d_in, const int* in_sizes, int n_in,
                              void* d_out, int out_size, void* d_ws, size_t ws_size,
                              hipStream_t stream)
{
    const float* input    = (const float*)d_in[0];
    const float* hiddens  = (const float*)d_in[1];
    const float* cells    = (const float*)d_in[2];
    const float* external = (const float*)d_in[3];
    const float* W_ai     = (const float*)d_in[4];
    const float* W_attn   = (const float*)d_in[5];
    const float* W_merge  = (const float*)d_in[6];
    const float* W_iou    = (const float*)d_in[7];
    const float* W_fi     = (const float*)d_in[8];
    const float* W_fh     = (const float*)d_in[9];
    const float* g_merge  = (const float*)d_in[10];
    const float* b_merge  = (const float*)d_in[11];
    const float* g_f      = (const float*)d_in[12];
    const float* b_f      = (const float*)d_in[13];
    const float* g_i      = (const float*)d_in[14];
    const float* b_i      = (const float*)d_in[15];
    const float* g_o      = (const float*)d_in[16];
    const float* b_o      = (const float*)d_in[17];
    const float* g_u      = (const float*)d_in[18];
    const float* b_u      = (const float*)d_in[19];
    const float* g_c      = (const float*)d_in[20];
    const float* b_c      = (const float*)d_in[21];

    float* ws = (float*)d_ws;
    float* ws_lp     = ws;              // 4096
    float* ws_fh     = ws + 4096;       // 65536
    float* ws_fi     = ws + 69632;      // 2048
    float* ws_frs    = ws + 71680;      // 64
    float* ws_mm     = ws + 71744;      // 2048
    float* ws_fc     = ws + 73792;      // 2048
    float* ws_iou    = ws + 75840;      // 6144
    float* out = (float*)d_out;

    s1<<<512, 256, 0, stream>>>(hiddens, external, input, W_ai, W_fh, W_fi,
                                W_attn, ws_lp, ws_fh, ws_fi);
    s2<<<288, 256, 0, stream>>>(ws_lp, hiddens, W_merge, ws_fi, ws_fh,
                                ws_mm, ws_frs);
    s3<<<520, 256, 0, stream>>>(W_iou, ws_mm, input, g_merge, b_merge,
                                ws_fi, ws_fh, ws_frs, g_f, b_f, cells,
                                ws_iou, ws_fc);
    s4_tail<<<1, 256, 0, stream>>>(ws_iou, ws_fc, g_i, b_i, g_o, b_o,
                                   g_u, b_u, g_c, b_c, out);
}